// Round 9
// baseline (323.612 us; speedup 1.0000x reference)
//
#include <hip/hip_runtime.h>
#include <stdint.h>

// Problem constants (from reference)
#define BATCH 4
#define SEQ   2048   // T == C == 2048
#define EMB   1024   // KEY_SIZE == VALUE_SIZE == H*64
#define NH    16
#define HD    64

typedef __attribute__((ext_vector_type(4))) float  floatx4;
typedef __attribute__((ext_vector_type(8))) short  shortx8;   // 8 bf16 = 4 VGPRs (MFMA A/B operand)

__device__ __forceinline__ unsigned short f2bf(float f) {
  // round-to-nearest-even fp32 -> bf16
  unsigned u = __builtin_bit_cast(unsigned, f);
  u += 0x7FFFu + ((u >> 16) & 1u);
  return (unsigned short)(u >> 16);
}

__device__ __forceinline__ unsigned pack2bf(float a, float b) {
  // RNE-packed pair of bf16 (low = a, high = b)
  return (unsigned)f2bf(a) | ((unsigned)f2bf(b) << 16);
}

__device__ __forceinline__ unsigned packtrunc(float a, float b) {
  // truncating pack (low = bf16(a), high = bf16(b)) in ONE v_perm_b32
#if __has_builtin(__builtin_amdgcn_perm)
  return __builtin_amdgcn_perm(__builtin_bit_cast(unsigned, b),
                               __builtin_bit_cast(unsigned, a), 0x07060302u);
#else
  return (__builtin_bit_cast(unsigned, a) >> 16) |
         (__builtin_bit_cast(unsigned, b) & 0xFFFF0000u);
#endif
}

__device__ __forceinline__ float fexp2(float x) {
#if __has_builtin(__builtin_amdgcn_exp2f)
  return __builtin_amdgcn_exp2f(x);   // raw v_exp_f32, inputs bounded
#else
  return exp2f(x);
#endif
}

__device__ __forceinline__ void gl_lds16(const void* g, void* l) {
  // async global->LDS, 16B per lane; LDS dest = wave-uniform base + lane*16
  __builtin_amdgcn_global_load_lds((const __attribute__((address_space(1))) void*)g,
                                   (__attribute__((address_space(3))) void*)l,
                                   16, 0, 0);
}

// ---------------- fp32 -> bf16 casts ----------------
__device__ __forceinline__ void cast_body(const float* __restrict__ in,
                                          unsigned short* __restrict__ out, int bb, int t) {
  size_t i = (size_t)bb * 256 + t;
  const float4* p = (const float4*)in + i * 2;
  float4 f0 = p[0], f1 = p[1];
  uint4 o;
  o.x = pack2bf(f0.x, f0.y);
  o.y = pack2bf(f0.z, f0.w);
  o.z = pack2bf(f1.x, f1.y);
  o.w = pack2bf(f1.z, f1.w);
  ((uint4*)out)[i] = o;
}

__global__ __launch_bounds__(256) void cast_bf16(const float* __restrict__ in,
                                                 unsigned short* __restrict__ out) {
  cast_body(in, out, blockIdx.x, threadIdx.x);
}

// all 7 tensors in one launch: q/k/v (4096 blocks each) + 4 weights (512 each) = 14336
// HBM-bound: ~170 MB moved -> ~27 us, at the roofline. (Fusing the q/k/v cast into the
// GEMMs was tried twice — R6 raw, R8 with XCD swizzle + prefetch + cvt_pk — both net
// NEGATIVE: reg-staged A loses more GEMM throughput than the cast kernel costs, m151.)
__global__ __launch_bounds__(256) void cast_all(
    const float* __restrict__ q, const float* __restrict__ k, const float* __restrict__ v,
    const float* __restrict__ w0, const float* __restrict__ w1,
    const float* __restrict__ w2, const float* __restrict__ w3,
    unsigned short* __restrict__ oq, unsigned short* __restrict__ ok, unsigned short* __restrict__ ov,
    unsigned short* __restrict__ ow0, unsigned short* __restrict__ ow1,
    unsigned short* __restrict__ ow2, unsigned short* __restrict__ ow3) {
  int bb = blockIdx.x;
  const float* in; unsigned short* out;
  if      (bb < 4096)  { in = q;  out = oq; }
  else if (bb < 8192)  { in = k;  out = ok;  bb -= 4096; }
  else if (bb < 12288) { in = v;  out = ov;  bb -= 8192; }
  else if (bb < 12800) { in = w0; out = ow0; bb -= 12288; }
  else if (bb < 13312) { in = w1; out = ow1; bb -= 12800; }
  else if (bb < 13824) { in = w2; out = ow2; bb -= 13312; }
  else                 { in = w3; out = ow3; bb -= 13824; }
  cast_body(in, out, bb, threadIdx.x);
}

// 4 weight tensors in one launch (fallback path)
__global__ __launch_bounds__(256) void cast_w4(const float* __restrict__ i0, const float* __restrict__ i1,
                                               const float* __restrict__ i2, const float* __restrict__ i3,
                                               unsigned short* __restrict__ o0, unsigned short* __restrict__ o1,
                                               unsigned short* __restrict__ o2, unsigned short* __restrict__ o3) {
  int bb = blockIdx.x;
  const float* in; unsigned short* out;
  if      (bb < 512)  { in = i0; out = o0; }
  else if (bb < 1024) { in = i1; out = o1; bb -= 512; }
  else if (bb < 1536) { in = i2; out = o2; bb -= 1024; }
  else                { in = i3; out = o3; bb -= 1536; }
  cast_body(in, out, bb, threadIdx.x);
}

// ---------------- C[M,N] = scale * (A[M,K] @ Bt[N,K]^T)  (bf16 in, fp32 acc) ----------------
// 128x128 tile, BK=64 (16 k-iters), XOR-swizzled LDS (swizzle folded into DMA source addrs).
// T1 XCD-AWARE TILE SWIZZLE (R7-verified, -16 us total): all 8 n-tiles of an m-panel
// share lid%8 -> same XCD -> A-panel fetched into that XCD's L2 once. Grid must be (8,64[,z]).
// MODE 0: bf16 row-major C.  MODE 1: fp32 row-major C.
// MODE 2: bf16 C^T with pi c-permute, written via Ts LDS staging -> coalesced vT
#define TST 136   // Ts row stride in shorts (17*8: b128-aligned, bank-spread)
template <int MODE>
__device__ __forceinline__ void gemm_body(const unsigned short* __restrict__ A,
                                          const unsigned short* __restrict__ Bt,
                                          void* __restrict__ Cp, float cscale,
                                          unsigned short* As, unsigned short* Bs,
                                          unsigned short* Ts) {
  constexpr int N = EMB, K = EMB;
  constexpr int BM = 128, BN = 128, BK = 64;
  const int t = threadIdx.x, w = t >> 6, lane = t & 63;
  const int quad = lane >> 4, lrow = lane & 15;
  // XCD swizzle: lid%8 == hw XCD (round-robin heuristic); all 8 n-tiles of an m-panel
  // get the same lid%8 -> same XCD -> A-panel L2-resident after first fetch.
  const int lid = blockIdx.x + (int)(gridDim.x * blockIdx.y);   // 0..511
  const int xcd = lid & 7, slot = lid >> 3;                     // slot 0..63
  const int m0 = (xcd + 8 * (slot >> 3)) * BM;                  // m-panel 0..63
  const int n0 = (slot & 7) * BN;                               // n-tile 0..7
  const int wm = (w >> 1) * 64, wn = (w & 1) * 64;
  floatx4 acc[4][4] = {};

  // running swizzled source pointers: chunk q = i*256+t -> row r=q>>3, src chunk (q&7)^(r&7)
  const unsigned short* asrc[4];
  const unsigned short* bsrc[4];
#pragma unroll
  for (int i = 0; i < 4; i++) {
    int q = i * 256 + t;
    int r = q >> 3, kc = (q & 7) ^ (r & 7);
    asrc[i] = A + (size_t)(m0 + r) * K + kc * 8;
    bsrc[i] = Bt + (size_t)(n0 + r) * K + kc * 8;
  }

  for (int k0 = 0; k0 < K; k0 += BK) {
#pragma unroll
    for (int i = 0; i < 4; i++) {
      gl_lds16(asrc[i], (char*)As + (size_t)(i * 256 + w * 64) * 16);
      gl_lds16(bsrc[i], (char*)Bs + (size_t)(i * 256 + w * 64) * 16);
      asrc[i] += BK; bsrc[i] += BK;
    }
    __syncthreads();
#pragma unroll
    for (int ks = 0; ks < 2; ks++) {
      shortx8 a[4];
#pragma unroll
      for (int mi = 0; mi < 4; mi++) {
        int row = wm + mi * 16 + lrow;
        a[mi] = *(const shortx8*)(As + row * 64 + (((ks * 4 + quad) ^ (row & 7)) * 8));
      }
#pragma unroll
      for (int ni = 0; ni < 4; ni++) {
        int rowb = wn + ni * 16 + lrow;
        shortx8 b = *(const shortx8*)(Bs + rowb * 64 + (((ks * 4 + quad) ^ (rowb & 7)) * 8));
#pragma unroll
        for (int mi = 0; mi < 4; mi++)
          acc[mi][ni] = __builtin_amdgcn_mfma_f32_16x16x32_bf16(a[mi], b, acc[mi][ni], 0, 0, 0);
      }
    }
    __syncthreads();
  }

  if constexpr (MODE == 2) {
    // V^T + pi epilogue via Ts
#pragma unroll
    for (int u = 0; u < 2; u++)
#pragma unroll
      for (int ni = 0; ni < 4; ni++) {
        uint4 p;
        p.x = pack2bf(acc[2 * u][ni][0], acc[2 * u + 1][ni][0]);
        p.y = pack2bf(acc[2 * u][ni][1], acc[2 * u + 1][ni][1]);
        p.z = pack2bf(acc[2 * u][ni][2], acc[2 * u + 1][ni][2]);
        p.w = pack2bf(acc[2 * u][ni][3], acc[2 * u + 1][ni][3]);
        int col = wn + ni * 16 + lrow;           // n-local = (h-h0)*64 + d
        int cloc = wm + u * 32 + quad * 8;       // permuted c-slot base
        *(uint4*)(Ts + col * TST + cloc) = p;
      }
    __syncthreads();
    unsigned short* vTout = (unsigned short*)Cp;
    const int b = m0 >> 11, cbase = m0 & 2047, h0 = n0 >> 6;
#pragma unroll
    for (int i = 0; i < 8; i++) {
      int g = t + 256 * i;                       // 0..2047 output chunks
      int hh2 = g >> 10, d = (g >> 4) & 63, a = g & 15;
      uint4 v = *(const uint4*)(Ts + (hh2 * 64 + d) * TST + a * 8);
      *(uint4*)(vTout + ((size_t)((b * NH + h0 + hh2) * HD + d)) * SEQ + cbase + a * 8) = v;
    }
    __syncthreads();  // Ts reuse safety
  } else {
    // C/D layout: col = lane&15, row = quad*4 + reg
#pragma unroll
    for (int mi = 0; mi < 4; mi++)
#pragma unroll
      for (int ni = 0; ni < 4; ni++)
#pragma unroll
        for (int r = 0; r < 4; r++) {
          int row = m0 + wm + mi * 16 + quad * 4 + r;
          int col = n0 + wn + ni * 16 + lrow;
          float v = acc[mi][ni][r] * cscale;
          if constexpr (MODE == 1) ((float*)Cp)[(size_t)row * N + col] = v;
          else                     ((unsigned short*)Cp)[(size_t)row * N + col] = f2bf(v);
        }
  }
}

// Q/K projections. __launch_bounds__(256,3): R6 counters showed these run at 2 blocks/CU
// (Occupancy 25%) under (256,2); total regs ~148 (84 arch + 64 acc) fit the 170/wave cap
// of 3 waves/SIMD, and 3x32KB LDS fits -> force eligibility for 3 blocks/CU. A third
// resident block computes while another drains vmcnt at the barrier (the stall the
// 2-phase loop can't pipeline away; m97's 874 TF ran at ~3 blocks/CU).
__global__ __launch_bounds__(256, 3) void gemm_qk(
    const unsigned short* __restrict__ Xq, const unsigned short* __restrict__ Xk,
    const unsigned short* __restrict__ Wq, const unsigned short* __restrict__ Wk,
    unsigned short* __restrict__ Oq, unsigned short* __restrict__ Ok, float sq) {
  __shared__ unsigned short As[128 * 64];
  __shared__ unsigned short Bs[128 * 64];
  if (blockIdx.z == 0) gemm_body<0>(Xq, Wq, Oq, sq,   As, Bs, nullptr);
  else                 gemm_body<0>(Xk, Wk, Ok, 1.0f, As, Bs, nullptr);
}

// standalone variants (V-transpose + serial fallback path)
__global__ __launch_bounds__(256, 3) void gemm_b(const unsigned short* __restrict__ A,
                                                 const unsigned short* __restrict__ Bt,
                                                 unsigned short* __restrict__ C, float sc) {
  __shared__ unsigned short As[128 * 64];
  __shared__ unsigned short Bs[128 * 64];
  gemm_body<0>(A, Bt, C, sc, As, Bs, nullptr);
}
// gemm_vt keeps (256,2): 66.8 KB LDS caps it at 2 blocks/CU regardless.
__global__ __launch_bounds__(256, 2) void gemm_vt(const unsigned short* __restrict__ A,
                                                  const unsigned short* __restrict__ Bt,
                                                  unsigned short* __restrict__ C) {
  __shared__ unsigned short As[128 * 64];
  __shared__ unsigned short Bs[128 * 64];
  __shared__ unsigned short Ts[128 * TST];
  gemm_body<2>(A, Bt, C, 1.0f, As, Bs, Ts);
}
__global__ __launch_bounds__(256, 3) void gemm_o(const unsigned short* __restrict__ A,
                                                 const unsigned short* __restrict__ Bt,
                                                 float* __restrict__ C) {
  __shared__ unsigned short As[128 * 64];
  __shared__ unsigned short Bs[128 * 64];
  gemm_body<1>(A, Bt, C, 1.0f, As, Bs, nullptr);
}

// ---------------- flash attention (no-max softmax; Q in registers) ----------------
// Q pre-scaled by (1/8)*log2(e). 64-col K/V tiles, DMA staging, double-buffered.
// 64 q-rows per wave (256/block): halves per-q-row K/V LDS reads vs 32. Parked at
// ~89-91 us: R1-R4 showed the kernel sits at a mixed MFMA(32%)+VALU(37%)+LDS equilibrium
// insensitive to schedule (dbuf/T15/occupancy-halving all +-2%). VGPR 112 + AGPR accs
// -> (256,2); (256,4) spills (R7-prior session). Grid (64,8): all 8 q-tiles of one
// (b,h) share id%8 -> same XCD.
__global__ __launch_bounds__(256, 2) void flash_attn(const unsigned short* __restrict__ qp,
                                                     const unsigned short* __restrict__ kp,
                                                     const unsigned short* __restrict__ vT,
                                                     unsigned short* __restrict__ ao) {
  __shared__ unsigned short Ks[2][64 * 64];
  __shared__ unsigned short Vts[2][64 * 64];
  __shared__ unsigned short Ps[4][16 * 40];  // per-wave P (mi-split), stride 40 shorts
  const int h = blockIdx.x & (NH - 1), b = blockIdx.x >> 4;
  const int t0 = blockIdx.y * 256;
  const int t = threadIdx.x, w = t >> 6, lane = t & 63;
  const int quad = lane >> 4, lrow = lane & 15;

  // Q fragments in registers: A[m=lrow][k=32*kk+quad*8+j] -> 16B contiguous global loads
  shortx8 qfrag[2][4];
#pragma unroll
  for (int kk = 0; kk < 2; kk++)
#pragma unroll
    for (int mi = 0; mi < 4; mi++) {
      int row = w * 64 + mi * 16 + lrow;
      qfrag[kk][mi] = *(const shortx8*)(qp + ((size_t)(b * SEQ + t0 + row)) * EMB +
                                        h * HD + kk * 32 + quad * 8);
    }

  // per-lane running source pointers for K/V staging (swizzle folded into src)
  const unsigned short* ksrc[2];
  const unsigned short* vsrc[2];
#pragma unroll
  for (int i = 0; i < 2; i++) {
    int p = i * 256 + t;
    int r = p >> 3, kc = (p & 7) ^ (r & 7);
    ksrc[i] = kp + ((size_t)(b * SEQ + r)) * EMB + h * HD + kc * 8;
    vsrc[i] = vT + ((size_t)((b * NH + h) * HD + r)) * SEQ + kc * 8;  // d=r, cc=kc
  }

  float l_st[4][4] = {};
  floatx4 accO[4][4] = {};

  // prologue: stage tile 0 into buffer 0, drain
#pragma unroll
  for (int i = 0; i < 2; i++) {
    gl_lds16(ksrc[i], (char*)Ks[0] + (size_t)(i * 256 + w * 64) * 16);
    gl_lds16(vsrc[i], (char*)Vts[0] + (size_t)(i * 256 + w * 64) * 16);
    ksrc[i] += 64 * EMB;
    vsrc[i] += 64;
  }
  __syncthreads();

  for (int it = 0; it < SEQ / 64; ++it) {
    const int cur = it & 1;
    const unsigned short* Kc = Ks[cur];
    const unsigned short* Vc = Vts[cur];

    // issue DMA for tile it+1 into the other buffer (in flight during this tile's
    // compute; buf^1's readers finished at the previous iteration's trailing barrier)
    if (it + 1 < SEQ / 64) {
#pragma unroll
      for (int i = 0; i < 2; i++) {
        gl_lds16(ksrc[i], (char*)Ks[cur ^ 1] + (size_t)(i * 256 + w * 64) * 16);
        gl_lds16(vsrc[i], (char*)Vts[cur ^ 1] + (size_t)(i * 256 + w * 64) * 16);
        ksrc[i] += 64 * EMB;
        vsrc[i] += 64;
      }
    }

    // S = Qsc @ Ktile^T : wave w owns S rows [w*64, w*64+64); accS already log2-scaled
    floatx4 accS[4][4] = {};
    __builtin_amdgcn_s_setprio(1);
#pragma unroll
    for (int kk = 0; kk < 2; kk++) {
      int qk = quad + kk * 4;
#pragma unroll
      for (int ni = 0; ni < 4; ni++) {
        int rowb = ni * 16 + lrow;
        shortx8 bfr = *(const shortx8*)(Kc + rowb * 64 + ((qk ^ (rowb & 7)) * 8));
#pragma unroll
        for (int mi = 0; mi < 4; mi++)
          accS[mi][ni] = __builtin_amdgcn_mfma_f32_16x16x32_bf16(qfrag[kk][mi], bfr, accS[mi][ni], 0, 0, 0);
      }
    }
    __builtin_amdgcn_s_setprio(0);

    // two half-passes over c: p = exp2(s'), pack -> Ps, PV over 32 c'
    // in-wave DS ordering makes write->read->overwrite safe without barriers
#pragma unroll
    for (int hh = 0; hh < 2; hh++) {
      shortx8 pafr[4];
#pragma unroll
      for (int mi = 0; mi < 4; mi++) {
#pragma unroll
        for (int r = 0; r < 4; r++) {
          float p0 = fexp2(accS[mi][2 * hh][r]);
          float p1 = fexp2(accS[mi][2 * hh + 1][r]);
          l_st[mi][r] += p0 + p1;
          *(unsigned*)(&Ps[w][(quad * 4 + r) * 40 + lrow * 2]) = packtrunc(p0, p1);
        }
        pafr[mi] = *(const shortx8*)(&Ps[w][lrow * 40 + quad * 8]);
      }
      __builtin_amdgcn_s_setprio(1);
#pragma unroll
      for (int nio = 0; nio < 4; nio++) {
        int d = nio * 16 + lrow;
        shortx8 bfr = *(const shortx8*)(Vc + d * 64 + ((((hh << 2) + quad) ^ (d & 7)) * 8));
#pragma unroll
        for (int mi = 0; mi < 4; mi++)
          accO[mi][nio] = __builtin_amdgcn_mfma_f32_16x16x32_bf16(pafr[mi], bfr, accO[mi][nio], 0, 0, 0);
      }
      __builtin_amdgcn_s_setprio(0);
    }

    // single barrier per tile: drains tile it+1's DMA (hidden under the compute above)
    // and certifies all waves finished reading buf[cur] before it is overwritten
    __syncthreads();
  }

  // epilogue: reduce l across the 16-lane row group, normalize, store bf16
#pragma unroll
  for (int mi = 0; mi < 4; mi++)
#pragma unroll
    for (int r = 0; r < 4; r++) {
      float l = l_st[mi][r];
      l += __shfl_xor(l, 1);
      l += __shfl_xor(l, 2);
      l += __shfl_xor(l, 4);
      l += __shfl_xor(l, 8);
      float inv = 1.0f / l;
#pragma unroll
      for (int nio = 0; nio < 4; nio++) accO[mi][nio][r] *= inv;
    }
#pragma unroll
  for (int mi = 0; mi < 4; mi++)
#pragma unroll
    for (int nio = 0; nio < 4; nio++)
#pragma unroll
      for (int r = 0; r < 4; r++) {
        int row = t0 + w * 64 + mi * 16 + quad * 4 + r;
        int col = h * HD + nio * 16 + lrow;
        ao[((size_t)(b * SEQ + row)) * EMB + col] = f2bf(accO[mi][nio][r]);
      }
}

extern "C" void kernel_launch(void* const* d_in, const int* in_sizes, int n_in,
                              void* d_out, int out_size, void* d_ws, size_t ws_size,
                              hipStream_t stream) {
  const float* queries = (const float*)d_in[0];
  const float* keys    = (const float*)d_in[1];
  const float* values  = (const float*)d_in[2];
  const float* Wq      = (const float*)d_in[3];
  const float* Wk      = (const float*)d_in[4];
  const float* Wv      = (const float*)d_in[5];
  const float* Wo      = (const float*)d_in[6];

  char* ws = (char*)d_ws;
  const size_t MB = 1ull << 20;
  const float SC2 = 0.125f * 1.44269504088896341f;  // (1/sqrt(64)) * log2(e), folded into q

  unsigned short* wq_b = (unsigned short*)(ws + 0 * MB);
  unsigned short* wk_b = (unsigned short*)(ws + 2 * MB);
  unsigned short* wv_b = (unsigned short*)(ws + 4 * MB);
  unsigned short* wo_b = (unsigned short*)(ws + 6 * MB);

  dim3 gg(EMB / 128, (BATCH * SEQ) / 128);  // (8, 64)
  dim3 fg(NH * BATCH, SEQ / 256);           // (64, 8) XCD-locality swizzle, 256 q-rows/block

  if (ws_size >= 104 * MB) {
    // batched path: Xq 8-24 (->ao), Xk 24-40, Xv 40-56, qp 56-72, kp 72-88, vT 88-104
    unsigned short* Xq = (unsigned short*)(ws + 8 * MB);
    unsigned short* Xk = (unsigned short*)(ws + 24 * MB);
    unsigned short* Xv = (unsigned short*)(ws + 40 * MB);
    unsigned short* qp = (unsigned short*)(ws + 56 * MB);
    unsigned short* kp = (unsigned short*)(ws + 72 * MB);
    unsigned short* vT = (unsigned short*)(ws + 88 * MB);
    unsigned short* ao = Xq;   // Xq dead after gemm_qk

    cast_all<<<14336, 256, 0, stream>>>(queries, keys, values, Wq, Wk, Wv, Wo,
                                        Xq, Xk, Xv, wq_b, wk_b, wv_b, wo_b);
    gemm_qk<<<dim3(gg.x, gg.y, 2), 256, 0, stream>>>(Xq, Xk, wq_b, wk_b, qp, kp, SC2);
    gemm_vt<<<gg, 256, 0, stream>>>(Xv, wv_b, vT);
    flash_attn<<<fg, 256, 0, stream>>>(qp, kp, vT, ao);
    gemm_o<<<gg, 256, 0, stream>>>(ao, wo_b, (float*)d_out);
  } else {
    // serial fallback (72 MB layout)
    unsigned short* X  = (unsigned short*)(ws + 8 * MB);
    unsigned short* qp = (unsigned short*)(ws + 24 * MB);
    unsigned short* kp = (unsigned short*)(ws + 40 * MB);
    unsigned short* vT = (unsigned short*)(ws + 56 * MB);
    unsigned short* ao = X;

    cast_w4<<<2048, 256, 0, stream>>>(Wq, Wk, Wv, Wo, wq_b, wk_b, wv_b, wo_b);
    cast_bf16<<<4096, 256, 0, stream>>>(queries, X);
    gemm_b<<<gg, 256, 0, stream>>>(X, wq_b, qp, SC2);
    cast_bf16<<<4096, 256, 0, stream>>>(keys, X);
    gemm_b<<<gg, 256, 0, stream>>>(X, wk_b, kp, 1.0f);
    cast_bf16<<<4096, 256, 0, stream>>>(values, X);
    gemm_vt<<<gg, 256, 0, stream>>>(X, wv_b, vT);
    flash_attn<<<fg, 256, 0, stream>>>(qp, kp, vT, ao);
    gemm_o<<<gg, 256, 0, stream>>>(ao, wo_b, (float*)d_out);
  }
}

// Round 10
// 305.167 us; speedup vs baseline: 1.0604x; 1.0604x over previous
//
#include <hip/hip_runtime.h>
#include <stdint.h>

// Problem constants (from reference)
#define BATCH 4
#define SEQ   2048   // T == C == 2048
#define EMB   1024   // KEY_SIZE == VALUE_SIZE == H*64
#define NH    16
#define HD    64

typedef __attribute__((ext_vector_type(4))) float  floatx4;
typedef __attribute__((ext_vector_type(8))) short  shortx8;   // 8 bf16 = 4 VGPRs (MFMA A/B operand)

__device__ __forceinline__ unsigned short f2bf(float f) {
  // round-to-nearest-even fp32 -> bf16
  unsigned u = __builtin_bit_cast(unsigned, f);
  u += 0x7FFFu + ((u >> 16) & 1u);
  return (unsigned short)(u >> 16);
}

__device__ __forceinline__ unsigned pack2bf(float a, float b) {
  // RNE-packed pair of bf16 (low = a, high = b)
  return (unsigned)f2bf(a) | ((unsigned)f2bf(b) << 16);
}

__device__ __forceinline__ unsigned packtrunc(float a, float b) {
  // truncating pack (low = bf16(a), high = bf16(b)) in ONE v_perm_b32
#if __has_builtin(__builtin_amdgcn_perm)
  return __builtin_amdgcn_perm(__builtin_bit_cast(unsigned, b),
                               __builtin_bit_cast(unsigned, a), 0x07060302u);
#else
  return (__builtin_bit_cast(unsigned, a) >> 16) |
         (__builtin_bit_cast(unsigned, b) & 0xFFFF0000u);
#endif
}

__device__ __forceinline__ float fexp2(float x) {
#if __has_builtin(__builtin_amdgcn_exp2f)
  return __builtin_amdgcn_exp2f(x);   // raw v_exp_f32, inputs bounded
#else
  return exp2f(x);
#endif
}

__device__ __forceinline__ void gl_lds16(const void* g, void* l) {
  // async global->LDS, 16B per lane; LDS dest = wave-uniform base + lane*16
  __builtin_amdgcn_global_load_lds((const __attribute__((address_space(1))) void*)g,
                                   (__attribute__((address_space(3))) void*)l,
                                   16, 0, 0);
}

// ---------------- fp32 -> bf16 casts ----------------
__device__ __forceinline__ void cast_body(const float* __restrict__ in,
                                          unsigned short* __restrict__ out, int bb, int t) {
  size_t i = (size_t)bb * 256 + t;
  const float4* p = (const float4*)in + i * 2;
  float4 f0 = p[0], f1 = p[1];
  uint4 o;
  o.x = pack2bf(f0.x, f0.y);
  o.y = pack2bf(f0.z, f0.w);
  o.z = pack2bf(f1.x, f1.y);
  o.w = pack2bf(f1.z, f1.w);
  ((uint4*)out)[i] = o;
}

__global__ __launch_bounds__(256) void cast_bf16(const float* __restrict__ in,
                                                 unsigned short* __restrict__ out) {
  cast_body(in, out, blockIdx.x, threadIdx.x);
}

// all 7 tensors in one launch: q/k/v (4096 blocks each) + 4 weights (512 each) = 14336
// HBM-bound: ~170 MB moved -> ~27 us, at the roofline. (Fusing the q/k/v cast into the
// GEMMs was tried twice — R6 raw, R8 with XCD swizzle + prefetch + cvt_pk — both net
// NEGATIVE: reg-staged A loses more GEMM throughput than the cast kernel costs, m151.)
__global__ __launch_bounds__(256) void cast_all(
    const float* __restrict__ q, const float* __restrict__ k, const float* __restrict__ v,
    const float* __restrict__ w0, const float* __restrict__ w1,
    const float* __restrict__ w2, const float* __restrict__ w3,
    unsigned short* __restrict__ oq, unsigned short* __restrict__ ok, unsigned short* __restrict__ ov,
    unsigned short* __restrict__ ow0, unsigned short* __restrict__ ow1,
    unsigned short* __restrict__ ow2, unsigned short* __restrict__ ow3) {
  int bb = blockIdx.x;
  const float* in; unsigned short* out;
  if      (bb < 4096)  { in = q;  out = oq; }
  else if (bb < 8192)  { in = k;  out = ok;  bb -= 4096; }
  else if (bb < 12288) { in = v;  out = ov;  bb -= 8192; }
  else if (bb < 12800) { in = w0; out = ow0; bb -= 12288; }
  else if (bb < 13312) { in = w1; out = ow1; bb -= 12800; }
  else if (bb < 13824) { in = w2; out = ow2; bb -= 13312; }
  else                 { in = w3; out = ow3; bb -= 13824; }
  cast_body(in, out, bb, threadIdx.x);
}

// 4 weight tensors in one launch (fallback path)
__global__ __launch_bounds__(256) void cast_w4(const float* __restrict__ i0, const float* __restrict__ i1,
                                               const float* __restrict__ i2, const float* __restrict__ i3,
                                               unsigned short* __restrict__ o0, unsigned short* __restrict__ o1,
                                               unsigned short* __restrict__ o2, unsigned short* __restrict__ o3) {
  int bb = blockIdx.x;
  const float* in; unsigned short* out;
  if      (bb < 512)  { in = i0; out = o0; }
  else if (bb < 1024) { in = i1; out = o1; bb -= 512; }
  else if (bb < 1536) { in = i2; out = o2; bb -= 1024; }
  else                { in = i3; out = o3; bb -= 1536; }
  cast_body(in, out, bb, threadIdx.x);
}

// ---------------- C[M,N] = scale * (A[M,K] @ Bt[N,K]^T)  (bf16 in, fp32 acc) ----------------
// 128x128 tile, templated BK (64 or 128), XOR-swizzled LDS (swizzle folded into DMA src).
// T1 XCD-AWARE TILE SWIZZLE (R7-verified, -16 us total): all 8 n-tiles of an m-panel
// share lid%8 -> same XCD -> A-panel fetched into that XCD's L2 once. Grid must be (8,64[,z]).
// BK=128 (R10): halves the per-K-step barrier count (the vmcnt(0)+lgkmcnt(0) drain at
// each __syncthreads) and doubles MFMA per drain, at ZERO occupancy cost — unlike m132
// (3->2 blocks/CU regression), these kernels are already at 2 blocks/CU and 2x64 KB LDS
// still fits. Swizzle generalizes: rows-per-issue (16) = 0 mod 8, so the XOR term
// (t>>4)&7 stays issue-independent; read-side bank structure is unchanged (conflicts
// were 0 at BK=64 and the addr bits mod 128B are identical).
// NOTE (R9): do NOT force __launch_bounds__(256,3) — the <=170-VGPR cap cost ~11 us.
// MODE 0: bf16 row-major C.  MODE 1: fp32 row-major C.
// MODE 2: bf16 C^T with pi c-permute, written via Ts LDS staging -> coalesced vT
#define TST 136   // Ts row stride in shorts (17*8: b128-aligned, bank-spread)
template <int MODE, int BK>
__device__ __forceinline__ void gemm_body(const unsigned short* __restrict__ A,
                                          const unsigned short* __restrict__ Bt,
                                          void* __restrict__ Cp, float cscale,
                                          unsigned short* As, unsigned short* Bs,
                                          unsigned short* Ts) {
  constexpr int N = EMB, K = EMB;
  constexpr int BM = 128, BN = 128;
  constexpr int LC  = (BK == 64) ? 3 : 4;  // log2(chunks per row)
  constexpr int CH  = BK / 8;              // 16B chunks per row
  constexpr int RPI = 256 >> LC;           // rows per DMA issue (32 or 16)
  constexpr int NI  = BM / RPI;            // DMA issues per tensor per K-step (4 or 8)
  const int t = threadIdx.x, w = t >> 6, lane = t & 63;
  const int quad = lane >> 4, lrow = lane & 15;
  // XCD swizzle: lid%8 == hw XCD (round-robin heuristic)
  const int lid = blockIdx.x + (int)(gridDim.x * blockIdx.y);   // 0..511
  const int xcd = lid & 7, slot = lid >> 3;                     // slot 0..63
  const int m0 = (xcd + 8 * (slot >> 3)) * BM;                  // m-panel 0..63
  const int n0 = (slot & 7) * BN;                               // n-tile 0..7
  const int wm = (w >> 1) * 64, wn = (w & 1) * 64;
  floatx4 acc[4][4] = {};

  // chunk q = i*256+t -> row r = i*RPI + (t>>LC), swizzled col chunk (t&(CH-1)) ^ (r&7);
  // (r&7) == ((t>>LC)&7) because RPI % 8 == 0 -> one per-lane base + i*RPI*K stride.
  const int tr = t >> LC;
  const int sc = (t & (CH - 1)) ^ (tr & 7);
  const unsigned short* asrc = A + (size_t)(m0 + tr) * K + sc * 8;
  const unsigned short* bsrc = Bt + (size_t)(n0 + tr) * K + sc * 8;

  for (int k0 = 0; k0 < K; k0 += BK) {
#pragma unroll
    for (int i = 0; i < NI; i++) {
      gl_lds16(asrc + (size_t)i * RPI * K, (char*)As + (size_t)(i * 256 + w * 64) * 16);
      gl_lds16(bsrc + (size_t)i * RPI * K, (char*)Bs + (size_t)(i * 256 + w * 64) * 16);
    }
    asrc += BK; bsrc += BK;
    __syncthreads();
#pragma unroll
    for (int ks = 0; ks < BK / 32; ks++) {
      shortx8 a[4];
#pragma unroll
      for (int mi = 0; mi < 4; mi++) {
        int row = wm + mi * 16 + lrow;
        a[mi] = *(const shortx8*)(As + row * CH * 8 + (((ks * 4 + quad) ^ (row & 7)) * 8));
      }
#pragma unroll
      for (int ni = 0; ni < 4; ni++) {
        int rowb = wn + ni * 16 + lrow;
        shortx8 b = *(const shortx8*)(Bs + rowb * CH * 8 + (((ks * 4 + quad) ^ (rowb & 7)) * 8));
#pragma unroll
        for (int mi = 0; mi < 4; mi++)
          acc[mi][ni] = __builtin_amdgcn_mfma_f32_16x16x32_bf16(a[mi], b, acc[mi][ni], 0, 0, 0);
      }
    }
    __syncthreads();
  }

  if constexpr (MODE == 2) {
    // V^T + pi epilogue via Ts
#pragma unroll
    for (int u = 0; u < 2; u++)
#pragma unroll
      for (int ni = 0; ni < 4; ni++) {
        uint4 p;
        p.x = pack2bf(acc[2 * u][ni][0], acc[2 * u + 1][ni][0]);
        p.y = pack2bf(acc[2 * u][ni][1], acc[2 * u + 1][ni][1]);
        p.z = pack2bf(acc[2 * u][ni][2], acc[2 * u + 1][ni][2]);
        p.w = pack2bf(acc[2 * u][ni][3], acc[2 * u + 1][ni][3]);
        int col = wn + ni * 16 + lrow;           // n-local = (h-h0)*64 + d
        int cloc = wm + u * 32 + quad * 8;       // permuted c-slot base
        *(uint4*)(Ts + col * TST + cloc) = p;
      }
    __syncthreads();
    unsigned short* vTout = (unsigned short*)Cp;
    const int b = m0 >> 11, cbase = m0 & 2047, h0 = n0 >> 6;
#pragma unroll
    for (int i = 0; i < 8; i++) {
      int g = t + 256 * i;                       // 0..2047 output chunks
      int hh2 = g >> 10, d = (g >> 4) & 63, a = g & 15;
      uint4 v = *(const uint4*)(Ts + (hh2 * 64 + d) * TST + a * 8);
      *(uint4*)(vTout + ((size_t)((b * NH + h0 + hh2) * HD + d)) * SEQ + cbase + a * 8) = v;
    }
    __syncthreads();  // Ts reuse safety
  } else {
    // C/D layout: col = lane&15, row = quad*4 + reg
#pragma unroll
    for (int mi = 0; mi < 4; mi++)
#pragma unroll
      for (int ni = 0; ni < 4; ni++)
#pragma unroll
        for (int r = 0; r < 4; r++) {
          int row = m0 + wm + mi * 16 + quad * 4 + r;
          int col = n0 + wn + ni * 16 + lrow;
          float v = acc[mi][ni][r] * cscale;
          if constexpr (MODE == 1) ((float*)Cp)[(size_t)row * N + col] = v;
          else                     ((unsigned short*)Cp)[(size_t)row * N + col] = f2bf(v);
        }
  }
}

// Q/K projections, BK=128 (64 KB LDS, still 2 blocks/CU)
__global__ __launch_bounds__(256, 2) void gemm_qk(
    const unsigned short* __restrict__ Xq, const unsigned short* __restrict__ Xk,
    const unsigned short* __restrict__ Wq, const unsigned short* __restrict__ Wk,
    unsigned short* __restrict__ Oq, unsigned short* __restrict__ Ok, float sq) {
  __shared__ unsigned short As[128 * 128];
  __shared__ unsigned short Bs[128 * 128];
  if (blockIdx.z == 0) gemm_body<0, 128>(Xq, Wq, Oq, sq,   As, Bs, nullptr);
  else                 gemm_body<0, 128>(Xk, Wk, Ok, 1.0f, As, Bs, nullptr);
}

// fallback-path bf16 GEMM (BK=64)
__global__ __launch_bounds__(256, 2) void gemm_b(const unsigned short* __restrict__ A,
                                                 const unsigned short* __restrict__ Bt,
                                                 unsigned short* __restrict__ C, float sc) {
  __shared__ unsigned short As[128 * 64];
  __shared__ unsigned short Bs[128 * 64];
  gemm_body<0, 64>(A, Bt, C, sc, As, Bs, nullptr);
}
// V-transpose GEMM keeps BK=64: Ts (34.8 KB) + 2x32 KB at BK=128 would be 98.8 KB -> 1 block/CU.
__global__ __launch_bounds__(256, 2) void gemm_vt(const unsigned short* __restrict__ A,
                                                  const unsigned short* __restrict__ Bt,
                                                  unsigned short* __restrict__ C) {
  __shared__ unsigned short As[128 * 64];
  __shared__ unsigned short Bs[128 * 64];
  __shared__ unsigned short Ts[128 * TST];
  gemm_body<2, 64>(A, Bt, C, 1.0f, As, Bs, Ts);
}
// output projection, BK=128
__global__ __launch_bounds__(256, 2) void gemm_o(const unsigned short* __restrict__ A,
                                                 const unsigned short* __restrict__ Bt,
                                                 float* __restrict__ C) {
  __shared__ unsigned short As[128 * 128];
  __shared__ unsigned short Bs[128 * 128];
  gemm_body<1, 128>(A, Bt, C, 1.0f, As, Bs, nullptr);
}

// ---------------- flash attention (no-max softmax; Q in registers) ----------------
// Q pre-scaled by (1/8)*log2(e). 64-col K/V tiles, DMA staging, double-buffered.
// 64 q-rows per wave (256/block): halves per-q-row K/V LDS reads vs 32. Parked at
// ~89-91 us: R1-R4 showed the kernel sits at a mixed MFMA(32%)+VALU(37%)+LDS equilibrium
// insensitive to schedule (dbuf/T15/occupancy-halving all +-2%). VGPR 112 + AGPR accs
// -> (256,2). Grid (64,8): all 8 q-tiles of one (b,h) share id%8 -> same XCD.
__global__ __launch_bounds__(256, 2) void flash_attn(const unsigned short* __restrict__ qp,
                                                     const unsigned short* __restrict__ kp,
                                                     const unsigned short* __restrict__ vT,
                                                     unsigned short* __restrict__ ao) {
  __shared__ unsigned short Ks[2][64 * 64];
  __shared__ unsigned short Vts[2][64 * 64];
  __shared__ unsigned short Ps[4][16 * 40];  // per-wave P (mi-split), stride 40 shorts
  const int h = blockIdx.x & (NH - 1), b = blockIdx.x >> 4;
  const int t0 = blockIdx.y * 256;
  const int t = threadIdx.x, w = t >> 6, lane = t & 63;
  const int quad = lane >> 4, lrow = lane & 15;

  // Q fragments in registers: A[m=lrow][k=32*kk+quad*8+j] -> 16B contiguous global loads
  shortx8 qfrag[2][4];
#pragma unroll
  for (int kk = 0; kk < 2; kk++)
#pragma unroll
    for (int mi = 0; mi < 4; mi++) {
      int row = w * 64 + mi * 16 + lrow;
      qfrag[kk][mi] = *(const shortx8*)(qp + ((size_t)(b * SEQ + t0 + row)) * EMB +
                                        h * HD + kk * 32 + quad * 8);
    }

  // per-lane running source pointers for K/V staging (swizzle folded into src)
  const unsigned short* ksrc[2];
  const unsigned short* vsrc[2];
#pragma unroll
  for (int i = 0; i < 2; i++) {
    int p = i * 256 + t;
    int r = p >> 3, kc = (p & 7) ^ (r & 7);
    ksrc[i] = kp + ((size_t)(b * SEQ + r)) * EMB + h * HD + kc * 8;
    vsrc[i] = vT + ((size_t)((b * NH + h) * HD + r)) * SEQ + kc * 8;  // d=r, cc=kc
  }

  float l_st[4][4] = {};
  floatx4 accO[4][4] = {};

  // prologue: stage tile 0 into buffer 0, drain
#pragma unroll
  for (int i = 0; i < 2; i++) {
    gl_lds16(ksrc[i], (char*)Ks[0] + (size_t)(i * 256 + w * 64) * 16);
    gl_lds16(vsrc[i], (char*)Vts[0] + (size_t)(i * 256 + w * 64) * 16);
    ksrc[i] += 64 * EMB;
    vsrc[i] += 64;
  }
  __syncthreads();

  for (int it = 0; it < SEQ / 64; ++it) {
    const int cur = it & 1;
    const unsigned short* Kc = Ks[cur];
    const unsigned short* Vc = Vts[cur];

    // issue DMA for tile it+1 into the other buffer (in flight during this tile's
    // compute; buf^1's readers finished at the previous iteration's trailing barrier)
    if (it + 1 < SEQ / 64) {
#pragma unroll
      for (int i = 0; i < 2; i++) {
        gl_lds16(ksrc[i], (char*)Ks[cur ^ 1] + (size_t)(i * 256 + w * 64) * 16);
        gl_lds16(vsrc[i], (char*)Vts[cur ^ 1] + (size_t)(i * 256 + w * 64) * 16);
        ksrc[i] += 64 * EMB;
        vsrc[i] += 64;
      }
    }

    // S = Qsc @ Ktile^T : wave w owns S rows [w*64, w*64+64); accS already log2-scaled
    floatx4 accS[4][4] = {};
    __builtin_amdgcn_s_setprio(1);
#pragma unroll
    for (int kk = 0; kk < 2; kk++) {
      int qk = quad + kk * 4;
#pragma unroll
      for (int ni = 0; ni < 4; ni++) {
        int rowb = ni * 16 + lrow;
        shortx8 bfr = *(const shortx8*)(Kc + rowb * 64 + ((qk ^ (rowb & 7)) * 8));
#pragma unroll
        for (int mi = 0; mi < 4; mi++)
          accS[mi][ni] = __builtin_amdgcn_mfma_f32_16x16x32_bf16(qfrag[kk][mi], bfr, accS[mi][ni], 0, 0, 0);
      }
    }
    __builtin_amdgcn_s_setprio(0);

    // two half-passes over c: p = exp2(s'), pack -> Ps, PV over 32 c'
    // in-wave DS ordering makes write->read->overwrite safe without barriers
#pragma unroll
    for (int hh = 0; hh < 2; hh++) {
      shortx8 pafr[4];
#pragma unroll
      for (int mi = 0; mi < 4; mi++) {
#pragma unroll
        for (int r = 0; r < 4; r++) {
          float p0 = fexp2(accS[mi][2 * hh][r]);
          float p1 = fexp2(accS[mi][2 * hh + 1][r]);
          l_st[mi][r] += p0 + p1;
          *(unsigned*)(&Ps[w][(quad * 4 + r) * 40 + lrow * 2]) = packtrunc(p0, p1);
        }
        pafr[mi] = *(const shortx8*)(&Ps[w][lrow * 40 + quad * 8]);
      }
      __builtin_amdgcn_s_setprio(1);
#pragma unroll
      for (int nio = 0; nio < 4; nio++) {
        int d = nio * 16 + lrow;
        shortx8 bfr = *(const shortx8*)(Vc + d * 64 + ((((hh << 2) + quad) ^ (d & 7)) * 8));
#pragma unroll
        for (int mi = 0; mi < 4; mi++)
          accO[mi][nio] = __builtin_amdgcn_mfma_f32_16x16x32_bf16(pafr[mi], bfr, accO[mi][nio], 0, 0, 0);
      }
      __builtin_amdgcn_s_setprio(0);
    }

    // single barrier per tile: drains tile it+1's DMA (hidden under the compute above)
    // and certifies all waves finished reading buf[cur] before it is overwritten
    __syncthreads();
  }

  // epilogue: reduce l across the 16-lane row group, normalize, store bf16
#pragma unroll
  for (int mi = 0; mi < 4; mi++)
#pragma unroll
    for (int r = 0; r < 4; r++) {
      float l = l_st[mi][r];
      l += __shfl_xor(l, 1);
      l += __shfl_xor(l, 2);
      l += __shfl_xor(l, 4);
      l += __shfl_xor(l, 8);
      float inv = 1.0f / l;
#pragma unroll
      for (int nio = 0; nio < 4; nio++) accO[mi][nio][r] *= inv;
    }
#pragma unroll
  for (int mi = 0; mi < 4; mi++)
#pragma unroll
    for (int nio = 0; nio < 4; nio++)
#pragma unroll
      for (int r = 0; r < 4; r++) {
        int row = t0 + w * 64 + mi * 16 + quad * 4 + r;
        int col = h * HD + nio * 16 + lrow;
        ao[((size_t)(b * SEQ + row)) * EMB + col] = f2bf(accO[mi][nio][r]);
      }
}

extern "C" void kernel_launch(void* const* d_in, const int* in_sizes, int n_in,
                              void* d_out, int out_size, void* d_ws, size_t ws_size,
                              hipStream_t stream) {
  const float* queries = (const float*)d_in[0];
  const float* keys    = (const float*)d_in[1];
  const float* values  = (const float*)d_in[2];
  const float* Wq      = (const float*)d_in[3];
  const float* Wk      = (const float*)d_in[4];
  const float* Wv      = (const float*)d_in[5];
  const float* Wo      = (const float*)d_in[6];

  char* ws = (char*)d_ws;
  const size_t MB = 1ull << 20;
  const float SC2 = 0.125f * 1.44269504088896341f;  // (1/sqrt(64)) * log2(e), folded into q

  unsigned short* wq_b = (unsigned short*)(ws + 0 * MB);
  unsigned short* wk_b = (unsigned short*)(ws + 2 * MB);
  unsigned short* wv_b = (unsigned short*)(ws + 4 * MB);
  unsigned short* wo_b = (unsigned short*)(ws + 6 * MB);

  dim3 gg(EMB / 128, (BATCH * SEQ) / 128);  // (8, 64)
  dim3 fg(NH * BATCH, SEQ / 256);           // (64, 8) XCD-locality swizzle, 256 q-rows/block

  if (ws_size >= 104 * MB) {
    // batched path: Xq 8-24 (->ao), Xk 24-40, Xv 40-56, qp 56-72, kp 72-88, vT 88-104
    unsigned short* Xq = (unsigned short*)(ws + 8 * MB);
    unsigned short* Xk = (unsigned short*)(ws + 24 * MB);
    unsigned short* Xv = (unsigned short*)(ws + 40 * MB);
    unsigned short* qp = (unsigned short*)(ws + 56 * MB);
    unsigned short* kp = (unsigned short*)(ws + 72 * MB);
    unsigned short* vT = (unsigned short*)(ws + 88 * MB);
    unsigned short* ao = Xq;   // Xq dead after gemm_qk

    cast_all<<<14336, 256, 0, stream>>>(queries, keys, values, Wq, Wk, Wv, Wo,
                                        Xq, Xk, Xv, wq_b, wk_b, wv_b, wo_b);
    gemm_qk<<<dim3(gg.x, gg.y, 2), 256, 0, stream>>>(Xq, Xk, wq_b, wk_b, qp, kp, SC2);
    gemm_vt<<<gg, 256, 0, stream>>>(Xv, wv_b, vT);
    flash_attn<<<fg, 256, 0, stream>>>(qp, kp, vT, ao);
    gemm_o<<<gg, 256, 0, stream>>>(ao, wo_b, (float*)d_out);
  } else {
    // serial fallback (72 MB layout)
    unsigned short* X  = (unsigned short*)(ws + 8 * MB);
    unsigned short* qp = (unsigned short*)(ws + 24 * MB);
    unsigned short* kp = (unsigned short*)(ws + 40 * MB);
    unsigned short* vT = (unsigned short*)(ws + 56 * MB);
    unsigned short* ao = X;

    cast_w4<<<2048, 256, 0, stream>>>(Wq, Wk, Wv, Wo, wq_b, wk_b, wv_b, wo_b);
    cast_bf16<<<4096, 256, 0, stream>>>(queries, X);
    gemm_b<<<gg, 256, 0, stream>>>(X, wq_b, qp, SC2);
    cast_bf16<<<4096, 256, 0, stream>>>(keys, X);
    gemm_b<<<gg, 256, 0, stream>>>(X, wk_b, kp, 1.0f);
    cast_bf16<<<4096, 256, 0, stream>>>(values, X);
    gemm_vt<<<gg, 256, 0, stream>>>(X, wv_b, vT);
    flash_attn<<<fg, 256, 0, stream>>>(qp, kp, vT, ao);
    gemm_o<<<gg, 256, 0, stream>>>(ao, wo_b, (float*)d_out);
  }
}